// Round 4
// baseline (1648.727 us; speedup 1.0000x reference)
//
#include <hip/hip_runtime.h>
#include <hip/hip_bf16.h>
#include <math.h>

#define BB 8
#define KK 19
#define PP 16384
#define CC 256
#define NN (BB*PP)           // 131072
#define KA_C 10.0f
#define IGNORE_L 255
#define CETHR 0.22314355131420976f   // -log(0.8)

// ws offsets (in floats)
#define OFF_FEATN   0                        // bf16[BB*CC*PP] = 16777216 floats worth
#define OFF_PROTO   16777216                 // 4864   [c][k]
#define OFF_COUNTS  (OFF_PROTO+4864)         // 32
#define OFF_SCAL    (OFF_COUNTS+32)          // 16 : 0 vmf, 1 consist, 2 ce_num, 3 ce_den, 4 contrast
#define OFF_UINIT   (OFF_SCAL+16)            // 4864  [c][k]
#define OFF_U       (OFF_UINIT+4864)         // 4864  [k][c]
#define OFF_A       (OFF_U+4864)             // KK*PP = 311296  [k][pix]
#define OFF_PBUF    (OFF_A+311296)           // BB*KK*PP = 2490368 fp32 [b][k][pix]
#define OFF_UPART   (OFF_PBUF+2490368)       // 512*4864
// end = 22083888 floats = 88.3 MB  (r1buf overlays head of PBUF in its dead window)

static __device__ __forceinline__ float bflo(unsigned int v){
    union{unsigned int i; float f;} x; x.i = v << 16; return x.f;
}
static __device__ __forceinline__ float bfhi(unsigned int v){
    union{unsigned int i; float f;} x; x.i = v & 0xffff0000u; return x.f;
}
static __device__ __forceinline__ unsigned short f2bf(float f){
    union{float f; unsigned int i;} x; x.f = f;
    unsigned int r = (x.i + 0x7fffu + ((x.i >> 16) & 1u)) >> 16;
    return (unsigned short)r;
}

// ---------------- proto segment-sum (raw f32 feat) ----------------
__global__ __launch_bounds__(256) void proto_kernel(const float* __restrict__ feat,
                                                    const int* __restrict__ target,
                                                    float* __restrict__ ws) {
    int blk = blockIdx.x;            // b*CC + c
    int b = blk >> 8;
    int c = blk & 255;
    int tid = threadIdx.x;
    const float* frow = feat + (size_t)(b*CC + c)*PP;
    const int*   trow = target + (size_t)b*PP;
    float acc[KK];
#pragma unroll
    for (int k=0;k<KK;k++) acc[k]=0.f;
    for (int p0 = tid*4; p0 < PP; p0 += 1024) {
        float4 v = *(const float4*)&frow[p0];
        int4   t = *(const int4*)&trow[p0];
#pragma unroll
        for (int k=0;k<KK;k++) {
            float s = acc[k];
            s += (t.x==k) ? v.x : 0.f;
            s += (t.y==k) ? v.y : 0.f;
            s += (t.z==k) ? v.z : 0.f;
            s += (t.w==k) ? v.w : 0.f;
            acc[k] = s;
        }
    }
    __shared__ float part[4][KK];
    int lane = tid & 63, w = tid >> 6;
#pragma unroll
    for (int k=0;k<KK;k++) {
        float v = acc[k];
#pragma unroll
        for (int s=32;s>0;s>>=1) v += __shfl_xor(v, s);
        if (lane==0) part[w][k]=v;
    }
    __syncthreads();
    if (tid < KK) {
        float s = part[0][tid]+part[1][tid]+part[2][tid]+part[3][tid];
        atomicAdd(&ws[OFF_PROTO + c*KK + tid], s);
    }
}

// ---------------- counts ----------------
__global__ __launch_bounds__(256) void counts_kernel(const int* __restrict__ target,
                                                     float* __restrict__ ws) {
    __shared__ int cnt[KK];
    if (threadIdx.x < KK) cnt[threadIdx.x]=0;
    __syncthreads();
    for (int i = blockIdx.x*256 + threadIdx.x; i < NN; i += gridDim.x*256) {
        int t = target[i];
        if (t >= 0 && t < KK) atomicAdd(&cnt[t], 1);
    }
    __syncthreads();
    if (threadIdx.x < KK) atomicAdd(&ws[OFF_COUNTS + threadIdx.x], (float)cnt[threadIdx.x]);
}

// ---------------- ss+conv fused: featn = bf16(feat/||feat||) ----------------
__global__ __launch_bounds__(256) void ssconv_kernel(const float* __restrict__ feat,
                                                     unsigned short* __restrict__ featn) {
    int n2 = blockIdx.x*256 + threadIdx.x;   // 65536 threads, 2 px each
    int b = n2 >> 13;
    int pix = (n2 & 8191) << 1;
    const float* base = feat + (size_t)b*CC*PP + pix;
    unsigned short* outp = featn + (size_t)b*CC*PP + pix;
    float s0=0.f, s1=0.f;
    for (int c0=0; c0<CC; c0+=8) {
        float2 v[8];
#pragma unroll
        for (int j=0;j<8;j++) v[j] = *(const float2*)&base[(size_t)(c0+j)*PP];
#pragma unroll
        for (int j=0;j<8;j++) { s0 = fmaf(v[j].x, v[j].x, s0); s1 = fmaf(v[j].y, v[j].y, s1); }
    }
    float r0 = 1.0f / fmaxf(sqrtf(s0), 1e-12f);
    float r1 = 1.0f / fmaxf(sqrtf(s1), 1e-12f);
    for (int c0=0; c0<CC; c0+=4) {
#pragma unroll
        for (int j=0;j<4;j++) {
            float2 v = *(const float2*)&base[(size_t)(c0+j)*PP];
            unsigned int lo = f2bf(v.x * r0);
            unsigned int hi = f2bf(v.y * r1);
            *(unsigned int*)&outp[(size_t)(c0+j)*PP] = (hi<<16) | lo;
        }
    }
}

// ---------------- setup: u_init, u0, contrast ----------------
__global__ __launch_bounds__(256) void setup_kernel(const float* __restrict__ pd,
                                                    float* __restrict__ ws) {
    int c = threadIdx.x;
    __shared__ float red[256];
    __shared__ float nrm[KK];
    __shared__ float lds_ui[256][KK];
    float cnts[KK], vi[KK];
#pragma unroll
    for (int k=0;k<KK;k++) cnts[k] = ws[OFF_COUNTS+k];
#pragma unroll
    for (int k=0;k<KK;k++) vi[k] = ws[OFF_PROTO + c*KK + k] / (cnts[k] + 1e-6f);
    for (int k=0;k<KK;k++) {
        red[c] = vi[k]*vi[k];
        __syncthreads();
        for (int s=128;s>0;s>>=1){ if (c<s) red[c]+=red[c+s]; __syncthreads(); }
        if (c==0) nrm[k] = fmaxf(sqrtf(red[0]), 1e-12f);
        __syncthreads();
    }
#pragma unroll
    for (int k=0;k<KK;k++) { vi[k] = vi[k]/nrm[k]; lds_ui[c][k] = vi[k]; ws[OFF_UINIT + c*KK + k] = vi[k]; }
    __syncthreads();
    float w0[KK];
#pragma unroll
    for (int k=0;k<KK;k++) w0[k] = (cnts[k]==0.f) ? pd[c*KK+k] : vi[k];
    for (int k=0;k<KK;k++) {
        red[c] = w0[k]*w0[k];
        __syncthreads();
        for (int s=128;s>0;s>>=1){ if (c<s) red[c]+=red[c+s]; __syncthreads(); }
        if (c==0) nrm[k] = fmaxf(sqrtf(red[0]), 1e-12f);
        __syncthreads();
    }
#pragma unroll
    for (int k=0;k<KK;k++) ws[OFF_U + k*CC + c] = w0[k] / nrm[k];
    float m[KK]; float Kn=0.f;
#pragma unroll
    for (int k=0;k<KK;k++){ m[k] = (cnts[k]==0.f)?0.f:1.f; Kn += m[k]; }
    float csum = 0.f;
    for (int idx = c; idx < KK*KK; idx += 256) {
        int k1 = idx / KK, k2 = idx % KK;
        if (m[k1]!=0.f && m[k2]!=0.f) {
            float g=0.f;
            for (int cc2=0; cc2<CC; cc2++) g += lds_ui[cc2][k1]*lds_ui[cc2][k2];
            csum += g;
        }
    }
    red[c]=csum; __syncthreads();
    for (int s=128;s>0;s>>=1){ if (c<s) red[c]+=red[c+s]; __syncthreads(); }
    if (c==0) ws[OFF_SCAL+4] = (red[0] - Kn) / (Kn * (Kn - 1.f));
}

// ---------------- PU fused: p (phase 1) + u-partials (phase 2) ----------------
__global__ __launch_bounds__(256) void pu_kernel(const unsigned short* __restrict__ featn,
                                                 const float* __restrict__ ws_u,
                                                 const float* __restrict__ abuf,
                                                 float* __restrict__ pbuf,
                                                 float* __restrict__ upart,
                                                 int uniform_a) {
    __shared__ float lu[4864];          // u [k][c]
    __shared__ float pl[256][21];       // p [px_local][k], stride 21 (coprime 32)
    int tid = threadIdx.x;
    for (int i=tid; i<4864; i+=256) lu[i] = ws_u[i];
    __syncthreads();
    int blk = blockIdx.x;               // 512: b = blk>>6, chunk = blk&63
    int b = blk >> 6;
    int pix0 = (blk & 63) * 256;
    int px = pix0 + tid;

    // ---- phase 1: this thread owns pixel px; compute p[k] ----
    const unsigned short* fcol = featn + (size_t)b*CC*PP + px;
    float d[KK];
#pragma unroll
    for (int k=0;k<KK;k++) d[k]=0.f;
    for (int c0=0; c0<CC; c0+=16) {
        float fv[16];
#pragma unroll
        for (int j=0;j<16;j++) fv[j] = bflo((unsigned int)fcol[(size_t)(c0+j)*PP]);
#pragma unroll
        for (int k=0;k<KK;k++) {
            float s = d[k];
#pragma unroll
            for (int j=0;j<16;j++) s = fmaf(fv[j], lu[k*CC+c0+j], s);
            d[k]=s;
        }
    }
    float e[KK]; float den=0.f;
#pragma unroll
    for (int k=0;k<KK;k++) {
        float av = uniform_a ? (1.0f/(float)KK) : abuf[k*PP + px];
        e[k] = av * __expf(KA_C * d[k]);
        den += e[k];
    }
    float inv = 1.0f/den;
#pragma unroll
    for (int k=0;k<KK;k++) {
        float p = e[k]*inv;
        pl[tid][k] = p;
        pbuf[((size_t)b*KK + k)*PP + px] = p;
    }
    __syncthreads();

    // ---- phase 2: this thread owns channel c=tid; accumulate u-partials ----
    const unsigned short* frow = featn + ((size_t)b*CC + tid)*PP + pix0;
    float acc[KK];
#pragma unroll
    for (int k=0;k<KK;k++) acc[k]=0.f;
    for (int j0=0; j0<256; j0+=32) {
        const uint4* rp = (const uint4*)&frow[j0];   // 64B = 32 bf16
        uint4 q[4];
#pragma unroll
        for (int t=0;t<4;t++) q[t] = rp[t];
        unsigned int vw[16];
#pragma unroll
        for (int t=0;t<4;t++) { vw[t*4+0]=q[t].x; vw[t*4+1]=q[t].y; vw[t*4+2]=q[t].z; vw[t*4+3]=q[t].w; }
#pragma unroll
        for (int jj=0;jj<16;jj++) {
            float flo = bflo(vw[jj]);
            float fhi = bfhi(vw[jj]);
            int j = j0 + jj*2;
#pragma unroll
            for (int k=0;k<KK;k++) acc[k] = fmaf(flo, pl[j][k], acc[k]);
#pragma unroll
            for (int k=0;k<KK;k++) acc[k] = fmaf(fhi, pl[j+1][k], acc[k]);
        }
    }
#pragma unroll
    for (int k=0;k<KK;k++) upart[(size_t)blk*4864 + tid*KK + k] = acc[k];
}

// ---------------- A: a = mean_b p ----------------
__global__ __launch_bounds__(256) void a_kernel(const float* __restrict__ pbuf,
                                                float* __restrict__ abuf) {
    int i = blockIdx.x*256 + threadIdx.x;   // KK*PP total
    float s=0.f;
#pragma unroll
    for (int b=0;b<BB;b++) s += pbuf[(size_t)b*KK*PP + i];
    abuf[i] = s * (1.0f/(float)BB);
}

// ---------------- R1: coalesced partial reduce 512 -> 8 ----------------
__global__ __launch_bounds__(256) void r1_kernel(const float* __restrict__ upart,
                                                 float* __restrict__ r1buf) {
    int blk = blockIdx.x;              // 152 = 8 ichunks * 19 echunks
    int echunk = blk % 19;
    int ichunk = blk / 19;
    int e = echunk*256 + threadIdx.x;  // 0..4863, coalesced
    float s = 0.f;
    int i0 = ichunk*64;
    for (int i=i0; i<i0+64; i++) s += upart[(size_t)i*4864 + e];
    r1buf[(size_t)ichunk*4864 + e] = s;
}

// ---------------- R2: final 8-way sum + normalize -> u ----------------
__global__ __launch_bounds__(256) void r2_kernel(const float* __restrict__ r1buf,
                                                 float* __restrict__ ws) {
    int k = blockIdx.x;   // 0..18
    int c = threadIdx.x;  // 0..255
    float s = 0.f;
#pragma unroll
    for (int i=0;i<8;i++) s += r1buf[(size_t)i*4864 + c*KK + k];
    __shared__ float red[256];
    red[c] = s*s; __syncthreads();
    for (int q=128;q>0;q>>=1){ if (c<q) red[c]+=red[c+q]; __syncthreads(); }
    float nrm = fmaxf(sqrtf(red[0]), 1e-12f);
    ws[OFF_U + k*CC + c] = s / nrm;
}

// ---------------- final losses ----------------
__global__ __launch_bounds__(256) void final_kernel(const unsigned short* __restrict__ featn,
                                                    const float* __restrict__ logit,
                                                    const int* __restrict__ target,
                                                    const float* __restrict__ ws_u,
                                                    const float* __restrict__ abuf,
                                                    float* __restrict__ scal) {
    __shared__ float lu[4864];
    for (int i=threadIdx.x; i<4864; i+=256) lu[i] = ws_u[i];
    __syncthreads();
    int n = blockIdx.x*256 + threadIdx.x;   // 131072 threads
    int b = n >> 14;
    int pix = n & (PP-1);
    const unsigned short* fcol = featn + (size_t)b*CC*PP + pix;
    float dot[KK];
#pragma unroll
    for (int k=0;k<KK;k++) dot[k]=0.f;
    for (int c0=0; c0<CC; c0+=16) {
        float fv[16];
#pragma unroll
        for (int j=0;j<16;j++) {
            unsigned int u16 = fcol[(size_t)(c0+j)*PP];
            fv[j] = bflo(u16);
        }
#pragma unroll
        for (int k=0;k<KK;k++) {
            float d = dot[k];
#pragma unroll
            for (int j=0;j<16;j++) d = fmaf(fv[j], lu[k*CC+c0+j], d);
            dot[k]=d;
        }
    }
    float e[KK]; float den=0.f;
#pragma unroll
    for (int k=0;k<KK;k++) {
        float av = abuf[k*PP + pix];
        e[k] = av * __expf(KA_C * dot[k]);
        den += e[k];
    }
    float inv = 1.0f/den;
    float vmf = 0.f;
#pragma unroll
    for (int k=0;k<KK;k++) {
        float av = abuf[k*PP + pix];
        vmf += -(e[k]*inv) * (__logf(av + 1e-6f) + KA_C * dot[k]);
    }
    float lg[KK]; float mx = -3.4e38f;
#pragma unroll
    for (int k=0;k<KK;k++) { lg[k] = logit[((size_t)b*KK + k)*PP + pix]; mx = fmaxf(mx, lg[k]); }
    float sme = 0.f;
#pragma unroll
    for (int k=0;k<KK;k++) sme += __expf(lg[k]-mx);
    float lse = mx + __logf(sme);
    float cons = 0.f;
#pragma unroll
    for (int k=0;k<KK;k++) cons += -(e[k]*inv) * (lg[k]-lse);
    int t = target[(size_t)b*PP + pix];
    float ce_n = 0.f, ce_d = 0.f;
    if (t != IGNORE_L) {
        float lt = 0.f;
#pragma unroll
        for (int k=0;k<KK;k++) lt = (t==k) ? lg[k] : lt;
        float ce = -(lt - lse);
        ce_n = fmaxf(ce, CETHR);
        ce_d = 1.f;
    }
    __shared__ float red[4][4];
    int lane = threadIdx.x & 63, w = threadIdx.x >> 6;
    float v0=vmf, v1=cons, v2=ce_n, v3=ce_d;
#pragma unroll
    for (int s=32;s>0;s>>=1) {
        v0 += __shfl_xor(v0, s); v1 += __shfl_xor(v1, s);
        v2 += __shfl_xor(v2, s); v3 += __shfl_xor(v3, s);
    }
    if (lane==0){ red[w][0]=v0; red[w][1]=v1; red[w][2]=v2; red[w][3]=v3; }
    __syncthreads();
    if (threadIdx.x==0) {
        atomicAdd(&scal[0], red[0][0]+red[1][0]+red[2][0]+red[3][0]);
        atomicAdd(&scal[1], red[0][1]+red[1][1]+red[2][1]+red[3][1]);
        atomicAdd(&scal[2], red[0][2]+red[1][2]+red[2][2]+red[3][2]);
        atomicAdd(&scal[3], red[0][3]+red[1][3]+red[2][3]+red[3][3]);
    }
}

// ---------------- finalize ----------------
__global__ __launch_bounds__(256) void finalize_kernel(const float* __restrict__ ws,
                                                       float* __restrict__ out) {
    if (blockIdx.x==0 && threadIdx.x==0) {
        float cnt_all = (float)BB*(float)PP*(float)KK;
        float vmf  = ws[OFF_SCAL+0] / cnt_all / logf((float)KK);
        float cons = ws[OFF_SCAL+1] / cnt_all;
        float ce   = ws[OFF_SCAL+2] / (ws[OFF_SCAL+3] + 1e-6f);
        float contrast = ws[OFF_SCAL+4];
        out[0] = ce + vmf + contrast + cons;
    }
    int i = blockIdx.x*256 + threadIdx.x;
    if (i < 4864) out[1+i] = ws[OFF_PROTO+i];
    if (blockIdx.x==0 && threadIdx.x < KK) out[1+4864+threadIdx.x] = ws[OFF_COUNTS+threadIdx.x];
}

extern "C" void kernel_launch(void* const* d_in, const int* in_sizes, int n_in,
                              void* d_out, int out_size, void* d_ws, size_t ws_size,
                              hipStream_t stream) {
    (void)in_sizes; (void)n_in; (void)out_size; (void)ws_size;
    const float* logit  = (const float*)d_in[0];
    const int*   target = (const int*)d_in[1];
    const float* feat   = (const float*)d_in[2];
    const float* pd     = (const float*)d_in[4];
    float* out = (float*)d_out;
    float* ws  = (float*)d_ws;

    unsigned short* featn = (unsigned short*)ws;     // OFF_FEATN
    float* ubuf  = ws + OFF_U;
    float* abuf  = ws + OFF_A;
    float* pbuf  = ws + OFF_PBUF;
    float* upart = ws + OFF_UPART;
    float* r1buf = ws + OFF_PBUF;                    // overlays pbuf head; dead window only
    float* scal  = ws + OFF_SCAL;

    hipMemsetAsync(ws + OFF_PROTO, 0, 4912*sizeof(float), stream);
    proto_kernel<<<BB*CC, 256, 0, stream>>>(feat, target, ws);
    counts_kernel<<<256, 256, 0, stream>>>(target, ws);
    setup_kernel<<<1, 256, 0, stream>>>(pd, ws);
    ssconv_kernel<<<256, 256, 0, stream>>>(feat, featn);
    // p0 + u-partials(p0)
    pu_kernel<<<512, 256, 0, stream>>>(featn, ubuf, abuf, pbuf, upart, 1);
    for (int it=1; it<10; it++) {
        a_kernel<<<(KK*PP)/256, 256, 0, stream>>>(pbuf, abuf);   // a_it
        r1_kernel<<<152, 256, 0, stream>>>(upart, r1buf);        // u_it
        r2_kernel<<<KK, 256, 0, stream>>>(r1buf, ws);
        pu_kernel<<<512, 256, 0, stream>>>(featn, ubuf, abuf, pbuf, upart, 0);  // p_it + partials
    }
    a_kernel<<<(KK*PP)/256, 256, 0, stream>>>(pbuf, abuf);       // a10
    r1_kernel<<<152, 256, 0, stream>>>(upart, r1buf);            // u10
    r2_kernel<<<KK, 256, 0, stream>>>(r1buf, ws);
    final_kernel<<<512, 256, 0, stream>>>(featn, logit, target, ubuf, abuf, scal);
    finalize_kernel<<<20, 256, 0, stream>>>(ws, out);
}

// Round 5
// 1033.841 us; speedup vs baseline: 1.5948x; 1.5948x over previous
//
#include <hip/hip_runtime.h>
#include <hip/hip_bf16.h>
#include <math.h>

#define BB 8
#define KK 19
#define PP 16384
#define CC 256
#define NN (BB*PP)           // 131072
#define KA_C 10.0f
#define IGNORE_L 255
#define CETHR 0.22314355131420976f   // -log(0.8)

// ws offsets (in floats)
#define OFF_FEATN   0                        // bf16[BB*CC*PP] = 16777216 floats worth
#define OFF_PROTO   16777216                 // 4864   [c][k]
#define OFF_COUNTS  (OFF_PROTO+4864)         // 32
#define OFF_SCAL    (OFF_COUNTS+32)          // 16
#define OFF_UINIT   (OFF_SCAL+16)            // 4864  [c][k]
#define OFF_U       (OFF_UINIT+4864)         // 4864  [k][c]
#define OFF_A       (OFF_U+4864)             // 4 x 311296 (a double-buffer, 2 halves each)
#define OFF_UPART   (OFF_A+1245184)          // 512*4864
#define OFF_R1      (OFF_UPART+2490368)      // 8*4864
// end = 20566320 floats = 82.3 MB

typedef __attribute__((ext_vector_type(8))) short short8v;
typedef __attribute__((ext_vector_type(4))) float f32x4;

static __device__ __forceinline__ float bflo(unsigned int v){
    union{unsigned int i; float f;} x; x.i = v << 16; return x.f;
}
static __device__ __forceinline__ unsigned short f2bf(float f){
    union{float f; unsigned int i;} x; x.f = f;
    unsigned int r = (x.i + 0x7fffu + ((x.i >> 16) & 1u)) >> 16;
    return (unsigned short)r;
}

// ---------------- proto segment-sum (raw f32 feat) ----------------
__global__ __launch_bounds__(256) void proto_kernel(const float* __restrict__ feat,
                                                    const int* __restrict__ target,
                                                    float* __restrict__ ws) {
    int blk = blockIdx.x;            // b*CC + c
    int b = blk >> 8;
    int c = blk & 255;
    int tid = threadIdx.x;
    const float* frow = feat + (size_t)(b*CC + c)*PP;
    const int*   trow = target + (size_t)b*PP;
    float acc[KK];
#pragma unroll
    for (int k=0;k<KK;k++) acc[k]=0.f;
    for (int p0 = tid*4; p0 < PP; p0 += 1024) {
        float4 v = *(const float4*)&frow[p0];
        int4   t = *(const int4*)&trow[p0];
#pragma unroll
        for (int k=0;k<KK;k++) {
            float s = acc[k];
            s += (t.x==k) ? v.x : 0.f;
            s += (t.y==k) ? v.y : 0.f;
            s += (t.z==k) ? v.z : 0.f;
            s += (t.w==k) ? v.w : 0.f;
            acc[k] = s;
        }
    }
    __shared__ float part[4][KK];
    int lane = tid & 63, w = tid >> 6;
#pragma unroll
    for (int k=0;k<KK;k++) {
        float v = acc[k];
#pragma unroll
        for (int s=32;s>0;s>>=1) v += __shfl_xor(v, s);
        if (lane==0) part[w][k]=v;
    }
    __syncthreads();
    if (tid < KK) {
        float s = part[0][tid]+part[1][tid]+part[2][tid]+part[3][tid];
        atomicAdd(&ws[OFF_PROTO + c*KK + tid], s);
    }
}

// ---------------- counts ----------------
__global__ __launch_bounds__(256) void counts_kernel(const int* __restrict__ target,
                                                     float* __restrict__ ws) {
    __shared__ int cnt[KK];
    if (threadIdx.x < KK) cnt[threadIdx.x]=0;
    __syncthreads();
    for (int i = blockIdx.x*256 + threadIdx.x; i < NN; i += gridDim.x*256) {
        int t = target[i];
        if (t >= 0 && t < KK) atomicAdd(&cnt[t], 1);
    }
    __syncthreads();
    if (threadIdx.x < KK) atomicAdd(&ws[OFF_COUNTS + threadIdx.x], (float)cnt[threadIdx.x]);
}

// ---------------- ss+conv fused: featn = bf16(feat/||feat||) ----------------
__global__ __launch_bounds__(256) void ssconv_kernel(const float* __restrict__ feat,
                                                     unsigned short* __restrict__ featn) {
    int n2 = blockIdx.x*256 + threadIdx.x;   // 65536 threads, 2 px each
    int b = n2 >> 13;
    int pix = (n2 & 8191) << 1;
    const float* base = feat + (size_t)b*CC*PP + pix;
    unsigned short* outp = featn + (size_t)b*CC*PP + pix;
    float s0=0.f, s1=0.f;
    for (int c0=0; c0<CC; c0+=8) {
        float2 v[8];
#pragma unroll
        for (int j=0;j<8;j++) v[j] = *(const float2*)&base[(size_t)(c0+j)*PP];
#pragma unroll
        for (int j=0;j<8;j++) { s0 = fmaf(v[j].x, v[j].x, s0); s1 = fmaf(v[j].y, v[j].y, s1); }
    }
    float r0 = 1.0f / fmaxf(sqrtf(s0), 1e-12f);
    float r1 = 1.0f / fmaxf(sqrtf(s1), 1e-12f);
    for (int c0=0; c0<CC; c0+=4) {
#pragma unroll
        for (int j=0;j<4;j++) {
            float2 v = *(const float2*)&base[(size_t)(c0+j)*PP];
            unsigned int lo = f2bf(v.x * r0);
            unsigned int hi = f2bf(v.y * r1);
            *(unsigned int*)&outp[(size_t)(c0+j)*PP] = (hi<<16) | lo;
        }
    }
}

// ---------------- setup: u_init, u0, contrast ----------------
__global__ __launch_bounds__(256) void setup_kernel(const float* __restrict__ pd,
                                                    float* __restrict__ ws) {
    int c = threadIdx.x;
    __shared__ float red[256];
    __shared__ float nrm[KK];
    __shared__ float lds_ui[256][KK];
    float cnts[KK], vi[KK];
#pragma unroll
    for (int k=0;k<KK;k++) cnts[k] = ws[OFF_COUNTS+k];
#pragma unroll
    for (int k=0;k<KK;k++) vi[k] = ws[OFF_PROTO + c*KK + k] / (cnts[k] + 1e-6f);
    for (int k=0;k<KK;k++) {
        red[c] = vi[k]*vi[k];
        __syncthreads();
        for (int s=128;s>0;s>>=1){ if (c<s) red[c]+=red[c+s]; __syncthreads(); }
        if (c==0) nrm[k] = fmaxf(sqrtf(red[0]), 1e-12f);
        __syncthreads();
    }
#pragma unroll
    for (int k=0;k<KK;k++) { vi[k] = vi[k]/nrm[k]; lds_ui[c][k] = vi[k]; ws[OFF_UINIT + c*KK + k] = vi[k]; }
    __syncthreads();
    float w0[KK];
#pragma unroll
    for (int k=0;k<KK;k++) w0[k] = (cnts[k]==0.f) ? pd[c*KK+k] : vi[k];
    for (int k=0;k<KK;k++) {
        red[c] = w0[k]*w0[k];
        __syncthreads();
        for (int s=128;s>0;s>>=1){ if (c<s) red[c]+=red[c+s]; __syncthreads(); }
        if (c==0) nrm[k] = fmaxf(sqrtf(red[0]), 1e-12f);
        __syncthreads();
    }
#pragma unroll
    for (int k=0;k<KK;k++) ws[OFF_U + k*CC + c] = w0[k] / nrm[k];
    float m[KK]; float Kn=0.f;
#pragma unroll
    for (int k=0;k<KK;k++){ m[k] = (cnts[k]==0.f)?0.f:1.f; Kn += m[k]; }
    float csum = 0.f;
    for (int idx = c; idx < KK*KK; idx += 256) {
        int k1 = idx / KK, k2 = idx % KK;
        if (m[k1]!=0.f && m[k2]!=0.f) {
            float g=0.f;
            for (int cc2=0; cc2<CC; cc2++) g += lds_ui[cc2][k1]*lds_ui[cc2][k2];
            csum += g;
        }
    }
    red[c]=csum; __syncthreads();
    for (int s=128;s>0;s>>=1){ if (c<s) red[c]+=red[c+s]; __syncthreads(); }
    if (c==0) ws[OFF_SCAL+4] = (red[0] - Kn) / (Kn * (Kn - 1.f));
}

// ---------------- PU via MFMA: dis -> p -> {a-acc, upart} ----------------
// grid 512: pxtile = blk&255 (64 px), bgrp = blk>>8 (4 b's). 4 warps.
__global__ __launch_bounds__(256) void pu_kernel(const unsigned short* __restrict__ featn,
                                                 const float* __restrict__ ubuf,
                                                 const float* __restrict__ aR0,
                                                 const float* __restrict__ aR1,
                                                 float* __restrict__ aW0,
                                                 float* __restrict__ aW1,
                                                 float* __restrict__ upart,
                                                 int uniform_a) {
    __shared__ __attribute__((aligned(16))) unsigned short u_lds[32*264];
    __shared__ __attribute__((aligned(16))) unsigned short p_lds[32*72];
    int tid = threadIdx.x;
    for (int i=tid; i<32*256; i+=256) {
        int k = i>>8, c = i&255;
        u_lds[k*264+c] = (k<KK) ? f2bf(ubuf[k*CC+c]) : (unsigned short)0;
    }
    __syncthreads();
    int blk = blockIdx.x;
    int pxtile = blk & 255;
    int bgrp = blk >> 8;
    int lane = tid & 63, wid = tid >> 6;
    int g = lane >> 4, lc = lane & 15;
    int px_w = pxtile*64 + wid*16;           // GEMM1 warp px base

    f32x4 upacc[4][2];
#pragma unroll
    for (int m=0;m<4;m++)
#pragma unroll
        for (int n=0;n<2;n++) upacc[m][n] = (f32x4){0.f,0.f,0.f,0.f};
    float aacc[2][4];
#pragma unroll
    for (int n=0;n<2;n++)
#pragma unroll
        for (int r=0;r<4;r++) aacc[n][r]=0.f;

    for (int bi=0; bi<4; bi++) {
        int bb = bgrp*4 + bi;
        const unsigned short* fb = featn + (size_t)bb*CC*PP;
        // ---- GEMM1: dis[16px][32kk] over K=c=256 ----
        f32x4 acc0 = (f32x4){0.f,0.f,0.f,0.f};
        f32x4 acc1 = (f32x4){0.f,0.f,0.f,0.f};
        int pxA = px_w + lc;
#pragma unroll 4
        for (int ks=0; ks<8; ks++) {
            int cbase = ks*32 + g*8;
            union { unsigned int u[4]; short8v s; } af;
#pragma unroll
            for (int j2=0;j2<4;j2++) {
                unsigned int lo = fb[(size_t)(cbase + 2*j2    )*PP + pxA];
                unsigned int hi = fb[(size_t)(cbase + 2*j2 + 1)*PP + pxA];
                af.u[j2] = lo | (hi<<16);
            }
            union { uint4 u4; short8v s; } bf0, bf1;
            bf0.u4 = *(const uint4*)&u_lds[(size_t)lc*264 + cbase];
            bf1.u4 = *(const uint4*)&u_lds[(size_t)(lc+16)*264 + cbase];
            acc0 = __builtin_amdgcn_mfma_f32_16x16x32_bf16(af.s, bf0.s, acc0, 0,0,0);
            acc1 = __builtin_amdgcn_mfma_f32_16x16x32_bf16(af.s, bf1.s, acc1, 0,0,0);
        }
        // ---- softmax rows (row = px = g*4+r, cols kk = lc / lc+16) ----
#pragma unroll
        for (int r=0;r<4;r++) {
            int pxg = px_w + g*4 + r;
            float a0, a1;
            if (uniform_a) { a0 = 1.0f/(float)KK; a1 = a0; }
            else {
                int k1 = (lc+16 > KK-1) ? (KK-1) : (lc+16);
                a0 = (aR0[(size_t)lc*PP+pxg] + aR1[(size_t)lc*PP+pxg])*0.125f;
                a1 = (aR0[(size_t)k1*PP+pxg] + aR1[(size_t)k1*PP+pxg])*0.125f;
            }
            float e0 = a0 * __expf(KA_C * acc0[r]);
            float e1 = (lc+16 < KK) ? a1 * __expf(KA_C * acc1[r]) : 0.f;
            float sv = e0 + e1;
            sv += __shfl_xor(sv,1); sv += __shfl_xor(sv,2);
            sv += __shfl_xor(sv,4); sv += __shfl_xor(sv,8);
            float inv = 1.0f/sv;
            float p0 = e0*inv, p1 = e1*inv;
            aacc[0][r] += p0; aacc[1][r] += p1;
            int pl = wid*16 + g*4 + r;
            p_lds[(size_t)lc*72 + pl]      = f2bf(p0);
            p_lds[(size_t)(lc+16)*72 + pl] = f2bf(p1);
        }
        __syncthreads();
        // ---- GEMM2: upart[c][kk] += featn[c][px] * p[px][kk], K=64 px ----
#pragma unroll
        for (int m=0;m<4;m++) {
            int c = wid*64 + m*16 + lc;
            const unsigned short* fr = fb + (size_t)c*PP + pxtile*64;
#pragma unroll
            for (int ks=0; ks<2; ks++) {
                int pxo = ks*32 + g*8;
                union { uint4 u4; short8v s; } af2, bp0, bp1;
                af2.u4 = *(const uint4*)&fr[pxo];
                bp0.u4 = *(const uint4*)&p_lds[(size_t)lc*72 + pxo];
                bp1.u4 = *(const uint4*)&p_lds[(size_t)(lc+16)*72 + pxo];
                upacc[m][0] = __builtin_amdgcn_mfma_f32_16x16x32_bf16(af2.s, bp0.s, upacc[m][0], 0,0,0);
                upacc[m][1] = __builtin_amdgcn_mfma_f32_16x16x32_bf16(af2.s, bp1.s, upacc[m][1], 0,0,0);
            }
        }
        __syncthreads();
    }
    // ---- write upart (per-block partial, summed over this block's 4 b) ----
#pragma unroll
    for (int m=0;m<4;m++) {
        int cb = wid*64 + m*16 + g*4;
#pragma unroll
        for (int n=0;n<2;n++) {
            int kk = lc + 16*n;
            if (kk < KK) {
#pragma unroll
                for (int r=0;r<4;r++)
                    upart[(size_t)blk*4864 + (size_t)(cb+r)*KK + kk] = upacc[m][n][r];
            }
        }
    }
    // ---- write a half-sums (sum of p over this block's 4 b) ----
    float* aOut = (bgrp==0) ? aW0 : aW1;
#pragma unroll
    for (int n=0;n<2;n++) {
        int kk = lc + 16*n;
        if (kk < KK) {
#pragma unroll
            for (int r=0;r<4;r++) {
                int pxg = px_w + g*4 + r;
                aOut[(size_t)kk*PP + pxg] = aacc[n][r];
            }
        }
    }
}

// ---------------- R1: coalesced partial reduce 512 -> 8 ----------------
__global__ __launch_bounds__(256) void r1_kernel(const float* __restrict__ upart,
                                                 float* __restrict__ r1buf) {
    int blk = blockIdx.x;              // 152 = 8 ichunks * 19 echunks
    int echunk = blk % 19;
    int ichunk = blk / 19;
    int e = echunk*256 + threadIdx.x;  // 0..4863, coalesced
    float s = 0.f;
    int i0 = ichunk*64;
    for (int i=i0; i<i0+64; i++) s += upart[(size_t)i*4864 + e];
    r1buf[(size_t)ichunk*4864 + e] = s;
}

// ---------------- R2: final 8-way sum + normalize -> u ----------------
__global__ __launch_bounds__(256) void r2_kernel(const float* __restrict__ r1buf,
                                                 float* __restrict__ ws) {
    int k = blockIdx.x;   // 0..18
    int c = threadIdx.x;  // 0..255
    float s = 0.f;
#pragma unroll
    for (int i=0;i<8;i++) s += r1buf[(size_t)i*4864 + c*KK + k];
    __shared__ float red[256];
    red[c] = s*s; __syncthreads();
    for (int q=128;q>0;q>>=1){ if (c<q) red[c]+=red[c+q]; __syncthreads(); }
    float nrm = fmaxf(sqrtf(red[0]), 1e-12f);
    ws[OFF_U + k*CC + c] = s / nrm;
}

// ---------------- final losses ----------------
__global__ __launch_bounds__(256) void final_kernel(const unsigned short* __restrict__ featn,
                                                    const float* __restrict__ logit,
                                                    const int* __restrict__ target,
                                                    const float* __restrict__ ws_u,
                                                    const float* __restrict__ aF0,
                                                    const float* __restrict__ aF1,
                                                    float* __restrict__ scal) {
    __shared__ float lu[4864];
    for (int i=threadIdx.x; i<4864; i+=256) lu[i] = ws_u[i];
    __syncthreads();
    int n = blockIdx.x*256 + threadIdx.x;   // 131072 threads
    int b = n >> 14;
    int pix = n & (PP-1);
    const unsigned short* fcol = featn + (size_t)b*CC*PP + pix;
    float dot[KK];
#pragma unroll
    for (int k=0;k<KK;k++) dot[k]=0.f;
    for (int c0=0; c0<CC; c0+=16) {
        float fv[16];
#pragma unroll
        for (int j=0;j<16;j++) {
            unsigned int u16 = fcol[(size_t)(c0+j)*PP];
            fv[j] = bflo(u16);
        }
#pragma unroll
        for (int k=0;k<KK;k++) {
            float d = dot[k];
#pragma unroll
            for (int j=0;j<16;j++) d = fmaf(fv[j], lu[k*CC+c0+j], d);
            dot[k]=d;
        }
    }
    float e[KK]; float den=0.f;
#pragma unroll
    for (int k=0;k<KK;k++) {
        float av = (aF0[(size_t)k*PP + pix] + aF1[(size_t)k*PP + pix])*0.125f;
        e[k] = av * __expf(KA_C * dot[k]);
        den += e[k];
    }
    float inv = 1.0f/den;
    float vmf = 0.f;
#pragma unroll
    for (int k=0;k<KK;k++) {
        float av = (aF0[(size_t)k*PP + pix] + aF1[(size_t)k*PP + pix])*0.125f;
        vmf += -(e[k]*inv) * (__logf(av + 1e-6f) + KA_C * dot[k]);
    }
    float lg[KK]; float mx = -3.4e38f;
#pragma unroll
    for (int k=0;k<KK;k++) { lg[k] = logit[((size_t)b*KK + k)*PP + pix]; mx = fmaxf(mx, lg[k]); }
    float sme = 0.f;
#pragma unroll
    for (int k=0;k<KK;k++) sme += __expf(lg[k]-mx);
    float lse = mx + __logf(sme);
    float cons = 0.f;
#pragma unroll
    for (int k=0;k<KK;k++) cons += -(e[k]*inv) * (lg[k]-lse);
    int t = target[(size_t)b*PP + pix];
    float ce_n = 0.f, ce_d = 0.f;
    if (t != IGNORE_L) {
        float lt = 0.f;
#pragma unroll
        for (int k=0;k<KK;k++) lt = (t==k) ? lg[k] : lt;
        float ce = -(lt - lse);
        ce_n = fmaxf(ce, CETHR);
        ce_d = 1.f;
    }
    __shared__ float red[4][4];
    int lane = threadIdx.x & 63, w = threadIdx.x >> 6;
    float v0=vmf, v1=cons, v2=ce_n, v3=ce_d;
#pragma unroll
    for (int s=32;s>0;s>>=1) {
        v0 += __shfl_xor(v0, s); v1 += __shfl_xor(v1, s);
        v2 += __shfl_xor(v2, s); v3 += __shfl_xor(v3, s);
    }
    if (lane==0){ red[w][0]=v0; red[w][1]=v1; red[w][2]=v2; red[w][3]=v3; }
    __syncthreads();
    if (threadIdx.x==0) {
        atomicAdd(&scal[0], red[0][0]+red[1][0]+red[2][0]+red[3][0]);
        atomicAdd(&scal[1], red[0][1]+red[1][1]+red[2][1]+red[3][1]);
        atomicAdd(&scal[2], red[0][2]+red[1][2]+red[2][2]+red[3][2]);
        atomicAdd(&scal[3], red[0][3]+red[1][3]+red[2][3]+red[3][3]);
    }
}

// ---------------- finalize ----------------
__global__ __launch_bounds__(256) void finalize_kernel(const float* __restrict__ ws,
                                                       float* __restrict__ out) {
    if (blockIdx.x==0 && threadIdx.x==0) {
        float cnt_all = (float)BB*(float)PP*(float)KK;
        float vmf  = ws[OFF_SCAL+0] / cnt_all / logf((float)KK);
        float cons = ws[OFF_SCAL+1] / cnt_all;
        float ce   = ws[OFF_SCAL+2] / (ws[OFF_SCAL+3] + 1e-6f);
        float contrast = ws[OFF_SCAL+4];
        out[0] = ce + vmf + contrast + cons;
    }
    int i = blockIdx.x*256 + threadIdx.x;
    if (i < 4864) out[1+i] = ws[OFF_PROTO+i];
    if (blockIdx.x==0 && threadIdx.x < KK) out[1+4864+threadIdx.x] = ws[OFF_COUNTS+threadIdx.x];
}

extern "C" void kernel_launch(void* const* d_in, const int* in_sizes, int n_in,
                              void* d_out, int out_size, void* d_ws, size_t ws_size,
                              hipStream_t stream) {
    (void)in_sizes; (void)n_in; (void)out_size; (void)ws_size;
    const float* logit  = (const float*)d_in[0];
    const int*   target = (const int*)d_in[1];
    const float* feat   = (const float*)d_in[2];
    const float* pd     = (const float*)d_in[4];
    float* out = (float*)d_out;
    float* ws  = (float*)d_ws;

    unsigned short* featn = (unsigned short*)ws;     // OFF_FEATN
    float* ubuf  = ws + OFF_U;
    float* upart = ws + OFF_UPART;
    float* r1buf = ws + OFF_R1;
    float* scal  = ws + OFF_SCAL;
    // a double-buffer: aBuf[i] halves at OFF_A + (2i+h)*311296
    float* aH[4];
    for (int q=0;q<4;q++) aH[q] = ws + OFF_A + (size_t)q*311296;

    hipMemsetAsync(ws + OFF_PROTO, 0, 4912*sizeof(float), stream);
    proto_kernel<<<BB*CC, 256, 0, stream>>>(feat, target, ws);
    counts_kernel<<<256, 256, 0, stream>>>(target, ws);
    setup_kernel<<<1, 256, 0, stream>>>(pd, ws);
    ssconv_kernel<<<256, 256, 0, stream>>>(feat, featn);

    for (int t=0; t<10; t++) {
        int ri = (t&1)*2;          // read pair index
        int wi = ((t+1)&1)*2;      // write pair index
        if (t > 0) {
            r1_kernel<<<152, 256, 0, stream>>>(upart, r1buf);
            r2_kernel<<<KK, 256, 0, stream>>>(r1buf, ws);
        }
        pu_kernel<<<512, 256, 0, stream>>>(featn, ubuf,
                                           aH[ri], aH[ri+1], aH[wi], aH[wi+1],
                                           upart, (t==0)?1:0);
    }
    r1_kernel<<<152, 256, 0, stream>>>(upart, r1buf);
    r2_kernel<<<KK, 256, 0, stream>>>(r1buf, ws);      // u10
    // after pass t=9, a10 lives in aBuf[0] = halves aH[0], aH[1]
    final_kernel<<<512, 256, 0, stream>>>(featn, logit, target, ubuf, aH[0], aH[1], scal);
    finalize_kernel<<<20, 256, 0, stream>>>(ws, out);
}

// Round 6
// 723.774 us; speedup vs baseline: 2.2780x; 1.4284x over previous
//
#include <hip/hip_runtime.h>
#include <hip/hip_bf16.h>
#include <math.h>

#define BB 8
#define KK 19
#define PP 16384
#define CC 256
#define NN (BB*PP)           // 131072
#define KA_C 10.0f
#define IGNORE_L 255
#define CETHR 0.22314355131420976f   // -log(0.8)

// ws offsets (in floats)
#define OFF_FEATN   0                        // bf16[BB*CC*PP] (c-major)  = 16777216 float-slots
#define OFF_FEATNT  16777216                 // bf16[BB*PP*CC] (px-major) = 16777216 float-slots
#define OFF_PROTO   33554432                 // 4864   [c][k]
#define OFF_COUNTS  (OFF_PROTO+4864)         // 32
#define OFF_SCAL    (OFF_COUNTS+32)          // 16
#define OFF_UINIT   (OFF_SCAL+16)            // 4864  [c][k]
#define OFF_U       (OFF_UINIT+4864)         // 4864  [k][c]
#define OFF_A       (OFF_U+4864)             // 4 x 311296 (a double-buffer, 2 halves each)
#define OFF_UPART   (OFF_A+1245184)          // 512*4864
#define OFF_R1      (OFF_UPART+2490368)      // 8*4864
// end = 37343536 floats = 149.4 MB

typedef __attribute__((ext_vector_type(8))) short short8v;
typedef __attribute__((ext_vector_type(4))) float f32x4;

static __device__ __forceinline__ float bflo(unsigned int v){
    union{unsigned int i; float f;} x; x.i = v << 16; return x.f;
}
static __device__ __forceinline__ unsigned short f2bf(float f){
    union{float f; unsigned int i;} x; x.f = f;
    unsigned int r = (x.i + 0x7fffu + ((x.i >> 16) & 1u)) >> 16;
    return (unsigned short)r;
}

// ---------------- proto segment-sum (raw f32 feat) ----------------
__global__ __launch_bounds__(256) void proto_kernel(const float* __restrict__ feat,
                                                    const int* __restrict__ target,
                                                    float* __restrict__ ws) {
    int blk = blockIdx.x;            // b*CC + c
    int b = blk >> 8;
    int c = blk & 255;
    int tid = threadIdx.x;
    const float* frow = feat + (size_t)(b*CC + c)*PP;
    const int*   trow = target + (size_t)b*PP;
    float acc[KK];
#pragma unroll
    for (int k=0;k<KK;k++) acc[k]=0.f;
    for (int p0 = tid*4; p0 < PP; p0 += 1024) {
        float4 v = *(const float4*)&frow[p0];
        int4   t = *(const int4*)&trow[p0];
#pragma unroll
        for (int k=0;k<KK;k++) {
            float s = acc[k];
            s += (t.x==k) ? v.x : 0.f;
            s += (t.y==k) ? v.y : 0.f;
            s += (t.z==k) ? v.z : 0.f;
            s += (t.w==k) ? v.w : 0.f;
            acc[k] = s;
        }
    }
    __shared__ float part[4][KK];
    int lane = tid & 63, w = tid >> 6;
#pragma unroll
    for (int k=0;k<KK;k++) {
        float v = acc[k];
#pragma unroll
        for (int s=32;s>0;s>>=1) v += __shfl_xor(v, s);
        if (lane==0) part[w][k]=v;
    }
    __syncthreads();
    if (tid < KK) {
        float s = part[0][tid]+part[1][tid]+part[2][tid]+part[3][tid];
        atomicAdd(&ws[OFF_PROTO + c*KK + tid], s);
    }
}

// ---------------- counts ----------------
__global__ __launch_bounds__(256) void counts_kernel(const int* __restrict__ target,
                                                     float* __restrict__ ws) {
    __shared__ int cnt[KK];
    if (threadIdx.x < KK) cnt[threadIdx.x]=0;
    __syncthreads();
    for (int i = blockIdx.x*256 + threadIdx.x; i < NN; i += gridDim.x*256) {
        int t = target[i];
        if (t >= 0 && t < KK) atomicAdd(&cnt[t], 1);
    }
    __syncthreads();
    if (threadIdx.x < KK) atomicAdd(&ws[OFF_COUNTS + threadIdx.x], (float)cnt[threadIdx.x]);
}

// ---------------- ss+conv fused: featn = bf16(feat/||feat||) ----------------
__global__ __launch_bounds__(256) void ssconv_kernel(const float* __restrict__ feat,
                                                     unsigned short* __restrict__ featn) {
    int n2 = blockIdx.x*256 + threadIdx.x;   // 65536 threads, 2 px each
    int b = n2 >> 13;
    int pix = (n2 & 8191) << 1;
    const float* base = feat + (size_t)b*CC*PP + pix;
    unsigned short* outp = featn + (size_t)b*CC*PP + pix;
    float s0=0.f, s1=0.f;
    for (int c0=0; c0<CC; c0+=8) {
        float2 v[8];
#pragma unroll
        for (int j=0;j<8;j++) v[j] = *(const float2*)&base[(size_t)(c0+j)*PP];
#pragma unroll
        for (int j=0;j<8;j++) { s0 = fmaf(v[j].x, v[j].x, s0); s1 = fmaf(v[j].y, v[j].y, s1); }
    }
    float r0 = 1.0f / fmaxf(sqrtf(s0), 1e-12f);
    float r1 = 1.0f / fmaxf(sqrtf(s1), 1e-12f);
    for (int c0=0; c0<CC; c0+=4) {
#pragma unroll
        for (int j=0;j<4;j++) {
            float2 v = *(const float2*)&base[(size_t)(c0+j)*PP];
            unsigned int lo = f2bf(v.x * r0);
            unsigned int hi = f2bf(v.y * r1);
            *(unsigned int*)&outp[(size_t)(c0+j)*PP] = (hi<<16) | lo;
        }
    }
}

// ---------------- transpose: featn [c][px] -> featn_T [px][c] ----------------
__global__ __launch_bounds__(256) void trans_kernel(const unsigned short* __restrict__ featn,
                                                    unsigned short* __restrict__ featn_T) {
    __shared__ unsigned short t_lds[64][260];   // 64 px x 256 c, pad 4
    int blk = blockIdx.x;        // 8 b * 256 px-chunks
    int b = blk >> 8;
    int px0 = (blk & 255) * 64;
    int tid = threadIdx.x;       // = c
    const unsigned short* src = featn + ((size_t)b*CC + tid)*PP + px0;
#pragma unroll
    for (int j4=0; j4<8; j4++) {
        uint4 q = *(const uint4*)&src[j4*8];
        unsigned int w[4] = {q.x, q.y, q.z, q.w};
#pragma unroll
        for (int h=0;h<4;h++) {
            t_lds[j4*8 + 2*h    ][tid] = (unsigned short)(w[h] & 0xffffu);
            t_lds[j4*8 + 2*h + 1][tid] = (unsigned short)(w[h] >> 16);
        }
    }
    __syncthreads();
    unsigned short* dst = featn_T + ((size_t)b*PP + px0)*CC;
    for (int i = tid; i < 64*128; i += 256) {
        int row = i >> 7, c2 = (i & 127) * 2;
        unsigned int v = (unsigned int)t_lds[row][c2] | ((unsigned int)t_lds[row][c2+1] << 16);
        *(unsigned int*)&dst[(size_t)row*CC + c2] = v;
    }
}

// ---------------- setup: u_init, u0, contrast ----------------
__global__ __launch_bounds__(256) void setup_kernel(const float* __restrict__ pd,
                                                    float* __restrict__ ws) {
    int c = threadIdx.x;
    __shared__ float red[256];
    __shared__ float nrm[KK];
    __shared__ float lds_ui[256][KK];
    float cnts[KK], vi[KK];
#pragma unroll
    for (int k=0;k<KK;k++) cnts[k] = ws[OFF_COUNTS+k];
#pragma unroll
    for (int k=0;k<KK;k++) vi[k] = ws[OFF_PROTO + c*KK + k] / (cnts[k] + 1e-6f);
    for (int k=0;k<KK;k++) {
        red[c] = vi[k]*vi[k];
        __syncthreads();
        for (int s=128;s>0;s>>=1){ if (c<s) red[c]+=red[c+s]; __syncthreads(); }
        if (c==0) nrm[k] = fmaxf(sqrtf(red[0]), 1e-12f);
        __syncthreads();
    }
#pragma unroll
    for (int k=0;k<KK;k++) { vi[k] = vi[k]/nrm[k]; lds_ui[c][k] = vi[k]; ws[OFF_UINIT + c*KK + k] = vi[k]; }
    __syncthreads();
    float w0[KK];
#pragma unroll
    for (int k=0;k<KK;k++) w0[k] = (cnts[k]==0.f) ? pd[c*KK+k] : vi[k];
    for (int k=0;k<KK;k++) {
        red[c] = w0[k]*w0[k];
        __syncthreads();
        for (int s=128;s>0;s>>=1){ if (c<s) red[c]+=red[c+s]; __syncthreads(); }
        if (c==0) nrm[k] = fmaxf(sqrtf(red[0]), 1e-12f);
        __syncthreads();
    }
#pragma unroll
    for (int k=0;k<KK;k++) ws[OFF_U + k*CC + c] = w0[k] / nrm[k];
    float m[KK]; float Kn=0.f;
#pragma unroll
    for (int k=0;k<KK;k++){ m[k] = (cnts[k]==0.f)?0.f:1.f; Kn += m[k]; }
    float csum = 0.f;
    for (int idx = c; idx < KK*KK; idx += 256) {
        int k1 = idx / KK, k2 = idx % KK;
        if (m[k1]!=0.f && m[k2]!=0.f) {
            float g=0.f;
            for (int cc2=0; cc2<CC; cc2++) g += lds_ui[cc2][k1]*lds_ui[cc2][k2];
            csum += g;
        }
    }
    red[c]=csum; __syncthreads();
    for (int s=128;s>0;s>>=1){ if (c<s) red[c]+=red[c+s]; __syncthreads(); }
    if (c==0) ws[OFF_SCAL+4] = (red[0] - Kn) / (Kn * (Kn - 1.f));
}

// ---------------- PU via MFMA: dis -> p -> {a-acc, upart} ----------------
// grid 512: pxtile = blk&255 (64 px), bgrp = blk>>8 (4 b's). 4 warps.
__global__ __launch_bounds__(256) void pu_kernel(const unsigned short* __restrict__ featn,
                                                 const unsigned short* __restrict__ featn_T,
                                                 const float* __restrict__ ubuf,
                                                 const float* __restrict__ aR0,
                                                 const float* __restrict__ aR1,
                                                 float* __restrict__ aW0,
                                                 float* __restrict__ aW1,
                                                 float* __restrict__ upart,
                                                 int uniform_a) {
    __shared__ __attribute__((aligned(16))) unsigned short u_lds[32*264];
    __shared__ __attribute__((aligned(16))) unsigned short p_lds[32*72];
    int tid = threadIdx.x;
    for (int i=tid; i<32*256; i+=256) {
        int k = i>>8, c = i&255;
        u_lds[k*264+c] = (k<KK) ? f2bf(ubuf[k*CC+c]) : (unsigned short)0;
    }
    __syncthreads();
    int blk = blockIdx.x;
    int pxtile = blk & 255;
    int bgrp = blk >> 8;
    int lane = tid & 63, wid = tid >> 6;
    int g = lane >> 4, lc = lane & 15;
    int px_w = pxtile*64 + wid*16;           // GEMM1 warp px base

    f32x4 upacc[4][2];
#pragma unroll
    for (int m=0;m<4;m++)
#pragma unroll
        for (int n=0;n<2;n++) upacc[m][n] = (f32x4){0.f,0.f,0.f,0.f};
    float aacc[2][4];
#pragma unroll
    for (int n=0;n<2;n++)
#pragma unroll
        for (int r=0;r<4;r++) aacc[n][r]=0.f;

    for (int bi=0; bi<4; bi++) {
        int bb = bgrp*4 + bi;
        const unsigned short* fb = featn + (size_t)bb*CC*PP;
        const unsigned short* fTrow = featn_T + ((size_t)bb*PP + px_w + lc)*CC;
        // ---- GEMM1: dis[16px][32kk] over K=c=256 ----
        f32x4 acc0 = (f32x4){0.f,0.f,0.f,0.f};
        f32x4 acc1 = (f32x4){0.f,0.f,0.f,0.f};
#pragma unroll
        for (int ks=0; ks<8; ks++) {
            int cbase = ks*32 + g*8;
            union { uint4 u4; short8v s; } af, bf0, bf1;
            af.u4  = *(const uint4*)&fTrow[cbase];
            bf0.u4 = *(const uint4*)&u_lds[(size_t)lc*264 + cbase];
            bf1.u4 = *(const uint4*)&u_lds[(size_t)(lc+16)*264 + cbase];
            acc0 = __builtin_amdgcn_mfma_f32_16x16x32_bf16(af.s, bf0.s, acc0, 0,0,0);
            acc1 = __builtin_amdgcn_mfma_f32_16x16x32_bf16(af.s, bf1.s, acc1, 0,0,0);
        }
        // ---- softmax rows (row = px = g*4+r, cols kk = lc / lc+16) ----
#pragma unroll
        for (int r=0;r<4;r++) {
            int pxg = px_w + g*4 + r;
            float a0, a1;
            if (uniform_a) { a0 = 1.0f/(float)KK; a1 = a0; }
            else {
                int k1 = (lc+16 > KK-1) ? (KK-1) : (lc+16);
                a0 = (aR0[(size_t)lc*PP+pxg] + aR1[(size_t)lc*PP+pxg])*0.125f;
                a1 = (aR0[(size_t)k1*PP+pxg] + aR1[(size_t)k1*PP+pxg])*0.125f;
            }
            float e0 = a0 * __expf(KA_C * acc0[r]);
            float e1 = (lc+16 < KK) ? a1 * __expf(KA_C * acc1[r]) : 0.f;
            float sv = e0 + e1;
            sv += __shfl_xor(sv,1); sv += __shfl_xor(sv,2);
            sv += __shfl_xor(sv,4); sv += __shfl_xor(sv,8);
            float inv = 1.0f/sv;
            float p0 = e0*inv, p1 = e1*inv;
            aacc[0][r] += p0; aacc[1][r] += p1;
            int pl = wid*16 + g*4 + r;
            p_lds[(size_t)lc*72 + pl]      = f2bf(p0);
            p_lds[(size_t)(lc+16)*72 + pl] = f2bf(p1);
        }
        __syncthreads();
        // ---- GEMM2: upart[c][kk] += featn[c][px] * p[px][kk], K=64 px ----
#pragma unroll
        for (int m=0;m<4;m++) {
            int c = wid*64 + m*16 + lc;
            const unsigned short* fr = fb + (size_t)c*PP + pxtile*64;
#pragma unroll
            for (int ks=0; ks<2; ks++) {
                int pxo = ks*32 + g*8;
                union { uint4 u4; short8v s; } af2, bp0, bp1;
                af2.u4 = *(const uint4*)&fr[pxo];
                bp0.u4 = *(const uint4*)&p_lds[(size_t)lc*72 + pxo];
                bp1.u4 = *(const uint4*)&p_lds[(size_t)(lc+16)*72 + pxo];
                upacc[m][0] = __builtin_amdgcn_mfma_f32_16x16x32_bf16(af2.s, bp0.s, upacc[m][0], 0,0,0);
                upacc[m][1] = __builtin_amdgcn_mfma_f32_16x16x32_bf16(af2.s, bp1.s, upacc[m][1], 0,0,0);
            }
        }
        __syncthreads();
    }
    // ---- write upart (per-block partial, summed over this block's 4 b) ----
#pragma unroll
    for (int m=0;m<4;m++) {
        int cb = wid*64 + m*16 + g*4;
#pragma unroll
        for (int n=0;n<2;n++) {
            int kk = lc + 16*n;
            if (kk < KK) {
#pragma unroll
                for (int r=0;r<4;r++)
                    upart[(size_t)blk*4864 + (size_t)(cb+r)*KK + kk] = upacc[m][n][r];
            }
        }
    }
    // ---- write a half-sums (sum of p over this block's 4 b) ----
    float* aOut = (bgrp==0) ? aW0 : aW1;
#pragma unroll
    for (int n=0;n<2;n++) {
        int kk = lc + 16*n;
        if (kk < KK) {
#pragma unroll
            for (int r=0;r<4;r++) {
                int pxg = px_w + g*4 + r;
                aOut[(size_t)kk*PP + pxg] = aacc[n][r];
            }
        }
    }
}

// ---------------- R1: coalesced partial reduce 512 -> 8 ----------------
__global__ __launch_bounds__(256) void r1_kernel(const float* __restrict__ upart,
                                                 float* __restrict__ r1buf) {
    int blk = blockIdx.x;              // 152 = 8 ichunks * 19 echunks
    int echunk = blk % 19;
    int ichunk = blk / 19;
    int e = echunk*256 + threadIdx.x;  // 0..4863, coalesced
    float s = 0.f;
    int i0 = ichunk*64;
    for (int i=i0; i<i0+64; i++) s += upart[(size_t)i*4864 + e];
    r1buf[(size_t)ichunk*4864 + e] = s;
}

// ---------------- R2: final 8-way sum + normalize -> u ----------------
__global__ __launch_bounds__(256) void r2_kernel(const float* __restrict__ r1buf,
                                                 float* __restrict__ ws) {
    int k = blockIdx.x;   // 0..18
    int c = threadIdx.x;  // 0..255
    float s = 0.f;
#pragma unroll
    for (int i=0;i<8;i++) s += r1buf[(size_t)i*4864 + c*KK + k];
    __shared__ float red[256];
    red[c] = s*s; __syncthreads();
    for (int q=128;q>0;q>>=1){ if (c<q) red[c]+=red[c+q]; __syncthreads(); }
    float nrm = fmaxf(sqrtf(red[0]), 1e-12f);
    ws[OFF_U + k*CC + c] = s / nrm;
}

// ---------------- final losses ----------------
__global__ __launch_bounds__(256) void final_kernel(const unsigned short* __restrict__ featn,
                                                    const float* __restrict__ logit,
                                                    const int* __restrict__ target,
                                                    const float* __restrict__ ws_u,
                                                    const float* __restrict__ aF0,
                                                    const float* __restrict__ aF1,
                                                    float* __restrict__ scal) {
    __shared__ float lu[4864];
    for (int i=threadIdx.x; i<4864; i+=256) lu[i] = ws_u[i];
    __syncthreads();
    int n = blockIdx.x*256 + threadIdx.x;   // 131072 threads
    int b = n >> 14;
    int pix = n & (PP-1);
    const unsigned short* fcol = featn + (size_t)b*CC*PP + pix;
    float dot[KK];
#pragma unroll
    for (int k=0;k<KK;k++) dot[k]=0.f;
    for (int c0=0; c0<CC; c0+=16) {
        float fv[16];
#pragma unroll
        for (int j=0;j<16;j++) {
            unsigned int u16 = fcol[(size_t)(c0+j)*PP];
            fv[j] = bflo(u16);
        }
#pragma unroll
        for (int k=0;k<KK;k++) {
            float d = dot[k];
#pragma unroll
            for (int j=0;j<16;j++) d = fmaf(fv[j], lu[k*CC+c0+j], d);
            dot[k]=d;
        }
    }
    float e[KK]; float den=0.f;
#pragma unroll
    for (int k=0;k<KK;k++) {
        float av = (aF0[(size_t)k*PP + pix] + aF1[(size_t)k*PP + pix])*0.125f;
        e[k] = av * __expf(KA_C * dot[k]);
        den += e[k];
    }
    float inv = 1.0f/den;
    float vmf = 0.f;
#pragma unroll
    for (int k=0;k<KK;k++) {
        float av = (aF0[(size_t)k*PP + pix] + aF1[(size_t)k*PP + pix])*0.125f;
        vmf += -(e[k]*inv) * (__logf(av + 1e-6f) + KA_C * dot[k]);
    }
    float lg[KK]; float mx = -3.4e38f;
#pragma unroll
    for (int k=0;k<KK;k++) { lg[k] = logit[((size_t)b*KK + k)*PP + pix]; mx = fmaxf(mx, lg[k]); }
    float sme = 0.f;
#pragma unroll
    for (int k=0;k<KK;k++) sme += __expf(lg[k]-mx);
    float lse = mx + __logf(sme);
    float cons = 0.f;
#pragma unroll
    for (int k=0;k<KK;k++) cons += -(e[k]*inv) * (lg[k]-lse);
    int t = target[(size_t)b*PP + pix];
    float ce_n = 0.f, ce_d = 0.f;
    if (t != IGNORE_L) {
        float lt = 0.f;
#pragma unroll
        for (int k=0;k<KK;k++) lt = (t==k) ? lg[k] : lt;
        float ce = -(lt - lse);
        ce_n = fmaxf(ce, CETHR);
        ce_d = 1.f;
    }
    __shared__ float red[4][4];
    int lane = threadIdx.x & 63, w = threadIdx.x >> 6;
    float v0=vmf, v1=cons, v2=ce_n, v3=ce_d;
#pragma unroll
    for (int s=32;s>0;s>>=1) {
        v0 += __shfl_xor(v0, s); v1 += __shfl_xor(v1, s);
        v2 += __shfl_xor(v2, s); v3 += __shfl_xor(v3, s);
    }
    if (lane==0){ red[w][0]=v0; red[w][1]=v1; red[w][2]=v2; red[w][3]=v3; }
    __syncthreads();
    if (threadIdx.x==0) {
        atomicAdd(&scal[0], red[0][0]+red[1][0]+red[2][0]+red[3][0]);
        atomicAdd(&scal[1], red[0][1]+red[1][1]+red[2][1]+red[3][1]);
        atomicAdd(&scal[2], red[0][2]+red[1][2]+red[2][2]+red[3][2]);
        atomicAdd(&scal[3], red[0][3]+red[1][3]+red[2][3]+red[3][3]);
    }
}

// ---------------- finalize ----------------
__global__ __launch_bounds__(256) void finalize_kernel(const float* __restrict__ ws,
                                                       float* __restrict__ out) {
    if (blockIdx.x==0 && threadIdx.x==0) {
        float cnt_all = (float)BB*(float)PP*(float)KK;
        float vmf  = ws[OFF_SCAL+0] / cnt_all / logf((float)KK);
        float cons = ws[OFF_SCAL+1] / cnt_all;
        float ce   = ws[OFF_SCAL+2] / (ws[OFF_SCAL+3] + 1e-6f);
        float contrast = ws[OFF_SCAL+4];
        out[0] = ce + vmf + contrast + cons;
    }
    int i = blockIdx.x*256 + threadIdx.x;
    if (i < 4864) out[1+i] = ws[OFF_PROTO+i];
    if (blockIdx.x==0 && threadIdx.x < KK) out[1+4864+threadIdx.x] = ws[OFF_COUNTS+threadIdx.x];
}

extern "C" void kernel_launch(void* const* d_in, const int* in_sizes, int n_in,
                              void* d_out, int out_size, void* d_ws, size_t ws_size,
                              hipStream_t stream) {
    (void)in_sizes; (void)n_in; (void)out_size; (void)ws_size;
    const float* logit  = (const float*)d_in[0];
    const int*   target = (const int*)d_in[1];
    const float* feat   = (const float*)d_in[2];
    const float* pd     = (const float*)d_in[4];
    float* out = (float*)d_out;
    float* ws  = (float*)d_ws;

    unsigned short* featn   = (unsigned short*)ws;                    // OFF_FEATN
    unsigned short* featn_T = (unsigned short*)(ws + OFF_FEATNT);
    float* ubuf  = ws + OFF_U;
    float* upart = ws + OFF_UPART;
    float* r1buf = ws + OFF_R1;
    float* scal  = ws + OFF_SCAL;
    float* aH[4];
    for (int q=0;q<4;q++) aH[q] = ws + OFF_A + (size_t)q*311296;

    hipMemsetAsync(ws + OFF_PROTO, 0, 4912*sizeof(float), stream);
    proto_kernel<<<BB*CC, 256, 0, stream>>>(feat, target, ws);
    counts_kernel<<<256, 256, 0, stream>>>(target, ws);
    setup_kernel<<<1, 256, 0, stream>>>(pd, ws);
    ssconv_kernel<<<256, 256, 0, stream>>>(feat, featn);
    trans_kernel<<<BB*256, 256, 0, stream>>>(featn, featn_T);

    for (int t=0; t<10; t++) {
        int ri = (t&1)*2;          // read pair index
        int wi = ((t+1)&1)*2;      // write pair index
        if (t > 0) {
            r1_kernel<<<152, 256, 0, stream>>>(upart, r1buf);
            r2_kernel<<<KK, 256, 0, stream>>>(r1buf, ws);
        }
        pu_kernel<<<512, 256, 0, stream>>>(featn, featn_T, ubuf,
                                           aH[ri], aH[ri+1], aH[wi], aH[wi+1],
                                           upart, (t==0)?1:0);
    }
    r1_kernel<<<152, 256, 0, stream>>>(upart, r1buf);
    r2_kernel<<<KK, 256, 0, stream>>>(r1buf, ws);      // u10
    final_kernel<<<512, 256, 0, stream>>>(featn, logit, target, ubuf, aH[0], aH[1], scal);
    finalize_kernel<<<20, 256, 0, stream>>>(ws, out);
}